// Round 5
// baseline (91.410 us; speedup 1.0000x reference)
//
#include <hip/hip_runtime.h>
#include <math.h>
#include <stdint.h>

#define Bb 16
#define Tt 28
#define Nn 2048
#define Hh 32
#define LAGS 8
#define LN_EPS 1e-5f

#define KSTR 40    // Kl row stride (shorts): uniform 8 words/bank on b128 reads
#define VSTR 132   // Vl row stride: 132*2B=66 banks => 2nl spread, uniform reads
#define PSTR 132   // Pt row stride

typedef float f4 __attribute__((ext_vector_type(4)));
typedef short s8v __attribute__((ext_vector_type(8)));
typedef unsigned short u16x8 __attribute__((ext_vector_type(8)));

__device__ __forceinline__ unsigned short f2b(float f) {
    unsigned u = __float_as_uint(f);
    u += 0x7FFFu + ((u >> 16) & 1u);   // RNE
    return (unsigned short)(u >> 16);
}

// ---------------- delayed signal -> Vtg row 32 (bf16) ----------------
__global__ void k_delayed(const float* __restrict__ x,
                          const float* __restrict__ dlog,
                          unsigned short* __restrict__ Vtg) {
    int idx = blockIdx.x * blockDim.x + threadIdx.x; // over B*N
    float w[LAGS];
    float m = -1e30f;
    #pragma unroll
    for (int t = 0; t < LAGS; ++t) m = fmaxf(m, dlog[t]);
    float s = 0.f;
    #pragma unroll
    for (int t = 0; t < LAGS; ++t) { w[t] = __expf(dlog[t] - m); s += w[t]; }
    float inv = 1.f / s;
    if (idx >= Bb * Nn) return;
    int b = idx / Nn, n = idx % Nn;
    float acc = 0.f;
    #pragma unroll
    for (int t = 0; t < LAGS; ++t)
        acc += (w[t] * inv) * x[(size_t)b * Tt * Nn + (size_t)(Tt - 1 - t) * Nn + n];
    Vtg[((size_t)b * 33 + 32) * Nn + n] = f2b(acc);
}

// ---------------- fused QKV projection -> bf16 Q,K + transposed V ----------------
__global__ void k_qkv(const float* __restrict__ feat,
                      const float* __restrict__ Wq, const float* __restrict__ bq,
                      const float* __restrict__ Wk, const float* __restrict__ bk,
                      const float* __restrict__ Wv, const float* __restrict__ bv,
                      unsigned short* __restrict__ Qbf, unsigned short* __restrict__ Kbf,
                      unsigned short* __restrict__ Vtg) {
    __shared__ float WqT[Hh][Hh + 1], WkT[Hh][Hh + 1], WvT[Hh][Hh + 1];
    __shared__ float f[8][Hh];
    __shared__ __align__(16) unsigned short VT8[Hh][8];
    int tid = threadIdx.x;
    for (int i = tid; i < Hh * Hh; i += 256) {
        int h = i >> 5, k = i & 31;
        WqT[k][h] = Wq[i];
        WkT[k][h] = Wk[i];
        WvT[k][h] = Wv[i];
    }
    int n0 = blockIdx.x * 8;
    f[tid >> 5][tid & 31] = feat[(size_t)n0 * Hh + tid];
    __syncthreads();
    int lr = tid >> 5, h = tid & 31;
    float aq = bq[h], ak = bk[h], av = bv[h];
    #pragma unroll
    for (int k = 0; k < Hh; ++k) {
        float fv = f[lr][k];
        aq += fv * WqT[k][h];
        ak += fv * WkT[k][h];
        av += fv * WvT[k][h];
    }
    size_t o = (size_t)(n0 + lr) * Hh + h;
    Qbf[o] = f2b(aq);
    Kbf[o] = f2b(ak);
    VT8[h][lr] = f2b(av);
    __syncthreads();
    if (tid < 32) {
        int b = n0 >> 11, r0 = n0 & 2047;
        *(u16x8*)(Vtg + ((size_t)b * 33 + tid) * Nn + r0) = *(const u16x8*)&VT8[tid][0];
    }
}

// ---------------- MFMA flash attention (8 waves, dbuf K/V, 1 barrier/chunk) ----
// 512 threads = 8 waves; wave w owns 16 n-cols: n0w = ntile*128 + w*16.
// Swapped scores: S^T[m][n] = mfma(A=K_frag, B=Q_frag). m-chunk = 128.
__global__ __launch_bounds__(512)
void k_attn(const unsigned short* __restrict__ Qbf,
            const unsigned short* __restrict__ Kbf,
            const unsigned short* __restrict__ Vtg,
            const float* __restrict__ adj,
            const float* __restrict__ geo_w,
            const float* __restrict__ feat,
            float* __restrict__ comb) {
    __shared__ __align__(16) unsigned short Kl[2][128 * KSTR];   // [buf][m][k] padded
    __shared__ __align__(16) unsigned short Vl[2][48 * VSTR];    // [buf][h][m] rows 0..32 staged
    __shared__ __align__(16) unsigned short Pt[8][16 * PSTR];    // per-wave P tile [n][m]

    int tid = threadIdx.x;
    int wid = tid >> 6, lane = tid & 63;
    int nl = lane & 15, g4 = lane >> 4;

    int bid = blockIdx.x;
    int bidl = ((bid & 7) << 5) + (bid >> 3);   // XCD-chunked swizzle (256 = 8*32)
    int b = bidl & 15;
    int ntile = bidl >> 4;                      // 0..15
    int n0w = ntile * 128 + wid * 16;

    float geo = 1.f / (1.f + __expf(-geo_w[0]));
    float cs = (1.f - geo) * 0.17677669529663687f;  // (1-geo)/sqrt(32)
    float cg = geo * 5.f;

    // Q B-fragment (col = n = lane&15, k = g4*8+j)
    s8v qf = *(const s8v*)(Qbf + (((size_t)b * Nn + n0w + nl) << 5) + g4 * 8);

    f4 zf4 = {0.f, 0.f, 0.f, 0.f};
    f4 pacc[3];
    #pragma unroll
    for (int t = 0; t < 3; ++t) pacc[t] = zf4;
    float M = -INFINITY, S = 0.f;

    const unsigned short* Kg = Kbf + ((size_t)b * Nn * Hh);
    const unsigned short* Vg = Vtg + ((size_t)b * 33 * Nn);

    u16x8 kst, vst0, vst1;
    // issue global loads for chunk c (into regs); 512 K granules + 528 V granules
    auto load = [&](int c) {
        int m0 = c * 128;
        kst = *(const u16x8*)(Kg + (size_t)(m0 + (tid >> 2)) * 32 + (tid & 3) * 8);
        vst0 = *(const u16x8*)(Vg + (size_t)(tid >> 4) * Nn + m0 + (tid & 15) * 8);
        if (tid < 16) {
            int G = 512 + tid;
            vst1 = *(const u16x8*)(Vg + (size_t)(G >> 4) * Nn + m0 + (G & 15) * 8);
        }
    };
    // write staged regs to LDS buffer buf
    auto store = [&](int buf) {
        *(u16x8*)(Kl[buf] + (tid >> 2) * KSTR + (tid & 3) * 8) = kst;
        *(u16x8*)(Vl[buf] + (tid >> 4) * VSTR + (tid & 15) * 8) = vst0;
        if (tid < 16) {
            int G = 512 + tid;
            *(u16x8*)(Vl[buf] + (G >> 4) * VSTR + (G & 15) * 8) = vst1;
        }
    };

    load(0);
    store(0);
    __syncthreads();

    unsigned short* Pw = Pt[wid];
    for (int c = 0; c < Nn / 128; ++c) {
        int cur = c & 1;
        if (c + 1 < Nn / 128) load(c + 1);   // in flight during compute
        int m0 = c * 128;

        // QK^T (swapped): per 16-m group, A = K frag (row=m), B = Q frag (col=n)
        f4 sc[8];
        #pragma unroll
        for (int mg = 0; mg < 8; ++mg) {
            s8v kf = *(const s8v*)(Kl[cur] + (mg * 16 + nl) * KSTR + g4 * 8);
            sc[mg] = __builtin_amdgcn_mfma_f32_16x16x32_bf16(kf, qf, zf4, 0, 0, 0);
        }

        // blend + online softmax + pack P
        // sc[mg][r] = S^T[m = mg*16 + g4*4 + r][n = n0w + nl]
        {
            const float* arow = adj + (size_t)(n0w + nl) * Nn + m0 + g4 * 4;
            #pragma unroll
            for (int mg = 0; mg < 8; ++mg) {
                f4 av = *(const f4*)(arow + mg * 16);
                sc[mg][0] = cs * sc[mg][0] + cg * av[0];
                sc[mg][1] = cs * sc[mg][1] + cg * av[1];
                sc[mg][2] = cs * sc[mg][2] + cg * av[2];
                sc[mg][3] = cs * sc[mg][3] + cg * av[3];
            }
            float cm = -INFINITY;
            #pragma unroll
            for (int mg = 0; mg < 8; ++mg) {
                f4 s = sc[mg];
                cm = fmaxf(cm, fmaxf(fmaxf(s[0], s[1]), fmaxf(s[2], s[3])));
            }
            cm = fmaxf(cm, __shfl_xor(cm, 16));
            cm = fmaxf(cm, __shfl_xor(cm, 32));
            float nM = fmaxf(M, cm);
            float scl = __expf(M - nM);
            M = nM;
            float ps = 0.f;
            #pragma unroll
            for (int mg = 0; mg < 8; ++mg) {
                f4 s = sc[mg];
                float p0 = __expf(s[0] - nM), p1 = __expf(s[1] - nM);
                float p2 = __expf(s[2] - nM), p3 = __expf(s[3] - nM);
                ps += (p0 + p1) + (p2 + p3);
                unsigned lo = (unsigned)f2b(p0) | ((unsigned)f2b(p1) << 16);
                unsigned hi = (unsigned)f2b(p2) | ((unsigned)f2b(p3) << 16);
                *(uint2*)(Pw + nl * PSTR + mg * 16 + g4 * 4) = make_uint2(lo, hi);
            }
            ps += __shfl_xor(ps, 16);
            ps += __shfl_xor(ps, 32);
            S = S * scl + ps;
            #pragma unroll
            for (int t = 0; t < 3; ++t) pacc[t] *= scl;
        }

        // PV (+delayed-signal row 32): att^T[h][n] += V^T_frag * P^T_frag
        #pragma unroll
        for (int s4 = 0; s4 < 4; ++s4) {
            s8v pb = *(const s8v*)(Pw + nl * PSTR + s4 * 32 + g4 * 8);
            #pragma unroll
            for (int t = 0; t < 3; ++t) {
                s8v va = *(const s8v*)(Vl[cur] + (t * 16 + nl) * VSTR + s4 * 32 + g4 * 8);
                pacc[t] = __builtin_amdgcn_mfma_f32_16x16x32_bf16(va, pb, pacc[t], 0, 0, 0);
            }
        }

        if (c + 1 < Nn / 128) store(cur ^ 1);  // concurrent with other waves' compute
        __syncthreads();                        // stores visible + readers drained
    }

    // epilogue: comb = feat + attended + 0.1*prop
    // pacc[t][r] = att^T[h = t*16 + g4*4 + r][n = n0w + nl]
    {
        float invS = 1.f / S;
        float pp = __shfl(pacc[2][0], nl) * invS * 0.1f;  // h=32 lives on g4==0,reg0
        size_t o = ((size_t)b * Nn + n0w + nl) * Hh;
        #pragma unroll
        for (int t = 0; t < 2; ++t) {
            f4 fv = *(const f4*)(feat + o + t * 16 + g4 * 4);
            f4 ov = fv + pacc[t] * invS;
            ov[0] += pp; ov[1] += pp; ov[2] += pp; ov[3] += pp;
            *(f4*)(comb + o + t * 16 + g4 * 4) = ov;
        }
    }
}

// ---------------- output projection + LayerNorm ----------------
__global__ void k_projln(const float* __restrict__ comb,
                         const float* __restrict__ Wo, const float* __restrict__ bo,
                         const float* __restrict__ gamma, const float* __restrict__ beta,
                         float* __restrict__ out) {
    __shared__ float WoT[Hh][Hh + 1];
    __shared__ float f[8][Hh];
    int tid = threadIdx.x;
    for (int i = tid; i < Hh * Hh; i += 256) {
        WoT[i & 31][i >> 5] = Wo[i];
    }
    int row0 = blockIdx.x * 8;
    f[tid >> 5][tid & 31] = comb[(size_t)row0 * Hh + tid];
    __syncthreads();
    int lr = tid >> 5, h = tid & 31;
    float a = bo[h];
    #pragma unroll
    for (int k = 0; k < Hh; ++k) a += f[lr][k] * WoT[k][h];
    float mu = a;
    #pragma unroll
    for (int w = 1; w < 32; w <<= 1) mu += __shfl_xor(mu, w);
    mu *= (1.f / 32.f);
    float d = a - mu;
    float v = d * d;
    #pragma unroll
    for (int w = 1; w < 32; w <<= 1) v += __shfl_xor(v, w);
    v *= (1.f / 32.f);
    out[(size_t)row0 * Hh + tid] = d * rsqrtf(v + LN_EPS) * gamma[h] + beta[h];
}

extern "C" void kernel_launch(void* const* d_in, const int* in_sizes, int n_in,
                              void* d_out, int out_size, void* d_ws, size_t ws_size,
                              hipStream_t stream) {
    const float* x     = (const float*)d_in[0];
    const float* feat  = (const float*)d_in[1];
    const float* dlog  = (const float*)d_in[2];
    const float* Wq    = (const float*)d_in[3];
    const float* bq    = (const float*)d_in[4];
    const float* Wk    = (const float*)d_in[5];
    const float* bk    = (const float*)d_in[6];
    const float* Wv    = (const float*)d_in[7];
    const float* bv    = (const float*)d_in[8];
    const float* adj   = (const float*)d_in[9];
    const float* geo   = (const float*)d_in[10];
    const float* Wo    = (const float*)d_in[11];
    const float* bo    = (const float*)d_in[12];
    const float* gamma = (const float*)d_in[13];
    const float* beta  = (const float*)d_in[14];
    float* out = (float*)d_out;

    char* w = (char*)d_ws;
    unsigned short* Qbf = (unsigned short*)w;  w += (size_t)Bb * Nn * Hh * 2;
    unsigned short* Kbf = (unsigned short*)w;  w += (size_t)Bb * Nn * Hh * 2;
    unsigned short* Vtg = (unsigned short*)w;  w += (size_t)Bb * 33 * Nn * 2;
    float* comb = (float*)w;

    k_delayed<<<(Bb * Nn + 255) / 256, 256, 0, stream>>>(x, dlog, Vtg);
    k_qkv<<<Bb * Nn / 8, 256, 0, stream>>>(feat, Wq, bq, Wk, bk, Wv, bv, Qbf, Kbf, Vtg);
    k_attn<<<256, 512, 0, stream>>>(Qbf, Kbf, Vtg, adj, geo, feat, comb);
    k_projln<<<Bb * Nn / 8, 256, 0, stream>>>(comb, Wo, bo, gamma, beta, out);
}

// Round 6
// 90.307 us; speedup vs baseline: 1.0122x; 1.0122x over previous
//
#include <hip/hip_runtime.h>
#include <math.h>
#include <stdint.h>

#define Bb 16
#define Tt 28
#define Nn 2048
#define Hh 32
#define LAGS 8
#define LN_EPS 1e-5f

#define KSTR 40    // Kl row stride (shorts); 40/2=20 ≡ 4 mod 8 -> uniform banks on b128
#define VSTR 136   // Vl row stride; 68 ≡ 4 mod 8 -> uniform
#define PSTR 72    // Pt row stride (shorts) for 64-wide half-m P tile; 36 ≡ 4 mod 8

typedef float f4 __attribute__((ext_vector_type(4)));
typedef short s8v __attribute__((ext_vector_type(8)));
typedef unsigned short u16x8 __attribute__((ext_vector_type(8)));

__device__ __forceinline__ unsigned short f2b(float f) {
    unsigned u = __float_as_uint(f);
    u += 0x7FFFu + ((u >> 16) & 1u);   // RNE
    return (unsigned short)(u >> 16);
}

// ---------------- delayed signal -> Vtg row 32 (bf16) ----------------
__global__ void k_delayed(const float* __restrict__ x,
                          const float* __restrict__ dlog,
                          unsigned short* __restrict__ Vtg) {
    int idx = blockIdx.x * blockDim.x + threadIdx.x; // over B*N
    float w[LAGS];
    float m = -1e30f;
    #pragma unroll
    for (int t = 0; t < LAGS; ++t) m = fmaxf(m, dlog[t]);
    float s = 0.f;
    #pragma unroll
    for (int t = 0; t < LAGS; ++t) { w[t] = __expf(dlog[t] - m); s += w[t]; }
    float inv = 1.f / s;
    if (idx >= Bb * Nn) return;
    int b = idx / Nn, n = idx % Nn;
    float acc = 0.f;
    #pragma unroll
    for (int t = 0; t < LAGS; ++t)
        acc += (w[t] * inv) * x[(size_t)b * Tt * Nn + (size_t)(Tt - 1 - t) * Nn + n];
    Vtg[((size_t)b * 33 + 32) * Nn + n] = f2b(acc);
}

// ---------------- fused QKV projection -> bf16 Q,K + transposed V ----------------
__global__ void k_qkv(const float* __restrict__ feat,
                      const float* __restrict__ Wq, const float* __restrict__ bq,
                      const float* __restrict__ Wk, const float* __restrict__ bk,
                      const float* __restrict__ Wv, const float* __restrict__ bv,
                      unsigned short* __restrict__ Qbf, unsigned short* __restrict__ Kbf,
                      unsigned short* __restrict__ Vtg) {
    __shared__ float WqT[Hh][Hh + 1], WkT[Hh][Hh + 1], WvT[Hh][Hh + 1];
    __shared__ float f[8][Hh];
    __shared__ __align__(16) unsigned short VT8[Hh][8];
    int tid = threadIdx.x;
    for (int i = tid; i < Hh * Hh; i += 256) {
        int h = i >> 5, k = i & 31;
        WqT[k][h] = Wq[i];
        WkT[k][h] = Wk[i];
        WvT[k][h] = Wv[i];
    }
    int n0 = blockIdx.x * 8;
    f[tid >> 5][tid & 31] = feat[(size_t)n0 * Hh + tid];
    __syncthreads();
    int lr = tid >> 5, h = tid & 31;
    float aq = bq[h], ak = bk[h], av = bv[h];
    #pragma unroll
    for (int k = 0; k < Hh; ++k) {
        float fv = f[lr][k];
        aq += fv * WqT[k][h];
        ak += fv * WkT[k][h];
        av += fv * WvT[k][h];
    }
    size_t o = (size_t)(n0 + lr) * Hh + h;
    Qbf[o] = f2b(aq);
    Kbf[o] = f2b(ak);
    VT8[h][lr] = f2b(av);
    __syncthreads();
    if (tid < 32) {
        int b = n0 >> 11, r0 = n0 & 2047;
        *(u16x8*)(Vtg + ((size_t)b * 33 + tid) * Nn + r0) = *(const u16x8*)&VT8[tid][0];
    }
}

// ---------------- MFMA flash attention (16 waves, m-split pairs) ----------------
// 1024 threads = 16 waves. Wave wid: n-cols = ntile*128 + (wid&7)*16;
// m-half = (wid>>3): rows [64*wh, 64*wh+64) of each 128-chunk.
// Pair (w, w+8) merge their flash states at the end.
__global__ __launch_bounds__(1024, 4)
void k_attn(const unsigned short* __restrict__ Qbf,
            const unsigned short* __restrict__ Kbf,
            const unsigned short* __restrict__ Vtg,
            const float* __restrict__ adj,
            const float* __restrict__ geo_w,
            const float* __restrict__ feat,
            float* __restrict__ comb) {
    __shared__ __align__(16) unsigned short Kl[2][128 * KSTR];   // [buf][m][k]
    __shared__ __align__(16) unsigned short Vl[2][48 * VSTR];    // [buf][h][m] rows 0..32
    __shared__ __align__(16) unsigned short Pt[16][16 * PSTR];   // per-wave P [n][m-half]

    int tid = threadIdx.x;
    int wid = tid >> 6, lane = tid & 63;
    int nl = lane & 15, g4 = lane >> 4;
    int wh = wid >> 3;                          // m-half
    int wc = wid & 7;                           // n-col group

    int bid = blockIdx.x;
    int bidl = ((bid & 7) << 5) + (bid >> 3);   // XCD-chunked swizzle (256 = 8*32)
    int b = bidl & 15;
    int ntile = bidl >> 4;                      // 0..15
    int n0w = ntile * 128 + wc * 16;

    float geo = 1.f / (1.f + __expf(-geo_w[0]));
    float cs = (1.f - geo) * 0.17677669529663687f;  // (1-geo)/sqrt(32)
    float cg = geo * 5.f;

    // Q B-fragment (col = n = nl, k = g4*8+j)
    s8v qf = *(const s8v*)(Qbf + (((size_t)b * Nn + n0w + nl) << 5) + g4 * 8);

    f4 zf4 = {0.f, 0.f, 0.f, 0.f};
    f4 pacc[3];
    #pragma unroll
    for (int t = 0; t < 3; ++t) pacc[t] = zf4;
    float M = -INFINITY, S = 0.f;

    const unsigned short* Kg = Kbf + ((size_t)b * Nn * Hh);
    const unsigned short* Vg = Vtg + ((size_t)b * 33 * Nn);

    u16x8 kst, vst0, vst1;
    // K: 512 granules (m=G>>2, gs=G&3); V: 528 granules (row=G>>4, gc=G&15)
    auto load = [&](int c) {
        int m0 = c * 128;
        if (tid < 512) {
            kst = *(const u16x8*)(Kg + (size_t)(m0 + (tid >> 2)) * 32 + (tid & 3) * 8);
        } else {
            int G = tid - 512;
            vst0 = *(const u16x8*)(Vg + (size_t)(G >> 4) * Nn + m0 + (G & 15) * 8);
        }
        if (tid < 16)
            vst1 = *(const u16x8*)(Vg + (size_t)32 * Nn + m0 + tid * 8);
    };
    auto store = [&](int buf) {
        if (tid < 512) {
            *(u16x8*)(Kl[buf] + (tid >> 2) * KSTR + (tid & 3) * 8) = kst;
        } else {
            int G = tid - 512;
            *(u16x8*)(Vl[buf] + (G >> 4) * VSTR + (G & 15) * 8) = vst0;
        }
        if (tid < 16)
            *(u16x8*)(Vl[buf] + 32 * VSTR + tid * 8) = vst1;
    };

    load(0);
    store(0);
    __syncthreads();

    unsigned short* Pw = Pt[wid];
    const int NC = Nn / 128;
    for (int c = 0; c < NC; ++c) {
        int cur = c & 1;
        if (c + 1 < NC) load(c + 1);   // in flight during compute
        int m0 = c * 128;

        // QK^T (swapped), this wave's m-half: local mg 0..3
        f4 sc[4];
        #pragma unroll
        for (int mg = 0; mg < 4; ++mg) {
            s8v kf = *(const s8v*)(Kl[cur] + (wh * 64 + mg * 16 + nl) * KSTR + g4 * 8);
            sc[mg] = __builtin_amdgcn_mfma_f32_16x16x32_bf16(kf, qf, zf4, 0, 0, 0);
        }

        // blend + online softmax + pack P
        // sc[mg][r] = S^T[m = wh*64 + mg*16 + g4*4 + r][n0w + nl]
        {
            const float* arow = adj + (size_t)(n0w + nl) * Nn + m0 + wh * 64 + g4 * 4;
            #pragma unroll
            for (int mg = 0; mg < 4; ++mg) {
                f4 av = *(const f4*)(arow + mg * 16);
                sc[mg][0] = cs * sc[mg][0] + cg * av[0];
                sc[mg][1] = cs * sc[mg][1] + cg * av[1];
                sc[mg][2] = cs * sc[mg][2] + cg * av[2];
                sc[mg][3] = cs * sc[mg][3] + cg * av[3];
            }
            float cm = -INFINITY;
            #pragma unroll
            for (int mg = 0; mg < 4; ++mg) {
                f4 s = sc[mg];
                cm = fmaxf(cm, fmaxf(fmaxf(s[0], s[1]), fmaxf(s[2], s[3])));
            }
            cm = fmaxf(cm, __shfl_xor(cm, 16));
            cm = fmaxf(cm, __shfl_xor(cm, 32));
            float nM = fmaxf(M, cm);
            float scl = __expf(M - nM);
            M = nM;
            float ps = 0.f;
            #pragma unroll
            for (int mg = 0; mg < 4; ++mg) {
                f4 s = sc[mg];
                float p0 = __expf(s[0] - nM), p1 = __expf(s[1] - nM);
                float p2 = __expf(s[2] - nM), p3 = __expf(s[3] - nM);
                ps += (p0 + p1) + (p2 + p3);
                unsigned lo = (unsigned)f2b(p0) | ((unsigned)f2b(p1) << 16);
                unsigned hi = (unsigned)f2b(p2) | ((unsigned)f2b(p3) << 16);
                *(uint2*)(Pw + nl * PSTR + mg * 16 + g4 * 4) = make_uint2(lo, hi);
            }
            ps += __shfl_xor(ps, 16);
            ps += __shfl_xor(ps, 32);
            S = S * scl + ps;
            #pragma unroll
            for (int t = 0; t < 3; ++t) pacc[t] *= scl;
        }

        // PV over this wave's m-half: 2 k-slices of 32
        #pragma unroll
        for (int s4 = 0; s4 < 2; ++s4) {
            s8v pb = *(const s8v*)(Pw + nl * PSTR + s4 * 32 + g4 * 8);
            #pragma unroll
            for (int t = 0; t < 3; ++t) {
                s8v va = *(const s8v*)(Vl[cur] + (t * 16 + nl) * VSTR + wh * 64 + s4 * 32 + g4 * 8);
                pacc[t] = __builtin_amdgcn_mfma_f32_16x16x32_bf16(va, pb, pacc[t], 0, 0, 0);
            }
        }

        if (c + 1 < NC) store(cur ^ 1);
        __syncthreads();
    }

    // ---- merge wave-pair flash states (reuse Pt region as float scratch) ----
    float* mbuf = (float*)&Pt[0][0];   // [8 pairs][64 lanes][14 floats]
    __syncthreads();                   // all PV reads of Pt done
    if (wh == 1) {
        float* mb = mbuf + ((size_t)wc * 64 + lane) * 14;
        mb[0] = M; mb[1] = S;
        #pragma unroll
        for (int t = 0; t < 3; ++t)
            #pragma unroll
            for (int r = 0; r < 4; ++r) mb[2 + t * 4 + r] = pacc[t][r];
    }
    __syncthreads();
    if (wh == 0) {
        const float* mb = mbuf + ((size_t)wc * 64 + lane) * 14;
        float M2 = mb[0], S2 = mb[1];
        float Mx = fmaxf(M, M2);
        float r1 = __expf(M - Mx), r2 = __expf(M2 - Mx);
        S = S * r1 + S2 * r2;
        #pragma unroll
        for (int t = 0; t < 3; ++t)
            #pragma unroll
            for (int r = 0; r < 4; ++r)
                pacc[t][r] = pacc[t][r] * r1 + mb[2 + t * 4 + r] * r2;

        // epilogue: comb = feat + attended + 0.1*prop
        float invS = 1.f / S;
        float pp = __shfl(pacc[2][0], nl) * invS * 0.1f;  // h=32 on g4==0,reg0
        size_t o = ((size_t)b * Nn + n0w + nl) * Hh;
        #pragma unroll
        for (int t = 0; t < 2; ++t) {
            f4 fv = *(const f4*)(feat + o + t * 16 + g4 * 4);
            f4 ov = fv + pacc[t] * invS;
            ov[0] += pp; ov[1] += pp; ov[2] += pp; ov[3] += pp;
            *(f4*)(comb + o + t * 16 + g4 * 4) = ov;
        }
    }
}

// ---------------- output projection + LayerNorm ----------------
__global__ void k_projln(const float* __restrict__ comb,
                         const float* __restrict__ Wo, const float* __restrict__ bo,
                         const float* __restrict__ gamma, const float* __restrict__ beta,
                         float* __restrict__ out) {
    __shared__ float WoT[Hh][Hh + 1];
    __shared__ float f[8][Hh];
    int tid = threadIdx.x;
    for (int i = tid; i < Hh * Hh; i += 256) {
        WoT[i & 31][i >> 5] = Wo[i];
    }
    int row0 = blockIdx.x * 8;
    f[tid >> 5][tid & 31] = comb[(size_t)row0 * Hh + tid];
    __syncthreads();
    int lr = tid >> 5, h = tid & 31;
    float a = bo[h];
    #pragma unroll
    for (int k = 0; k < Hh; ++k) a += f[lr][k] * WoT[k][h];
    float mu = a;
    #pragma unroll
    for (int w = 1; w < 32; w <<= 1) mu += __shfl_xor(mu, w);
    mu *= (1.f / 32.f);
    float d = a - mu;
    float v = d * d;
    #pragma unroll
    for (int w = 1; w < 32; w <<= 1) v += __shfl_xor(v, w);
    v *= (1.f / 32.f);
    out[(size_t)row0 * Hh + tid] = d * rsqrtf(v + LN_EPS) * gamma[h] + beta[h];
}

extern "C" void kernel_launch(void* const* d_in, const int* in_sizes, int n_in,
                              void* d_out, int out_size, void* d_ws, size_t ws_size,
                              hipStream_t stream) {
    const float* x     = (const float*)d_in[0];
    const float* feat  = (const float*)d_in[1];
    const float* dlog  = (const float*)d_in[2];
    const float* Wq    = (const float*)d_in[3];
    const float* bq    = (const float*)d_in[4];
    const float* Wk    = (const float*)d_in[5];
    const float* bk    = (const float*)d_in[6];
    const float* Wv    = (const float*)d_in[7];
    const float* bv    = (const float*)d_in[8];
    const float* adj   = (const float*)d_in[9];
    const float* geo   = (const float*)d_in[10];
    const float* Wo    = (const float*)d_in[11];
    const float* bo    = (const float*)d_in[12];
    const float* gamma = (const float*)d_in[13];
    const float* beta  = (const float*)d_in[14];
    float* out = (float*)d_out;

    char* w = (char*)d_ws;
    unsigned short* Qbf = (unsigned short*)w;  w += (size_t)Bb * Nn * Hh * 2;
    unsigned short* Kbf = (unsigned short*)w;  w += (size_t)Bb * Nn * Hh * 2;
    unsigned short* Vtg = (unsigned short*)w;  w += (size_t)Bb * 33 * Nn * 2;
    float* comb = (float*)w;

    k_delayed<<<(Bb * Nn + 255) / 256, 256, 0, stream>>>(x, dlog, Vtg);
    k_qkv<<<Bb * Nn / 8, 256, 0, stream>>>(feat, Wq, bq, Wk, bk, Wv, bv, Qbf, Kbf, Vtg);
    k_attn<<<256, 1024, 0, stream>>>(Qbf, Kbf, Vtg, adj, geo, feat, comb);
    k_projln<<<Bb * Nn / 8, 256, 0, stream>>>(comb, Wo, bo, gamma, beta, out);
}